// Round 3
// baseline (380.744 us; speedup 1.0000x reference)
//
#include <hip/hip_runtime.h>

constexpr int NZ   = 300, NX = 500, NPAD = 40;
constexpr int NZP  = NZ + NPAD;          // 340
constexpr int NXP  = NX + 2 * NPAD;      // 580 (divisible by 4)
constexpr int Bdim = 2, Cdim = 8;
constexpr int HW   = NZP * NXP;          // 197200
constexpr int S    = Bdim * Cdim * HW;   // 3155200
constexpr int NQ   = NXP / 4;            // 145 quads per row
constexpr int COLS = Bdim * Cdim * NQ;   // 2320 quad-columns
constexpr int LSEG = 4;                  // rows per thread (z-march)
constexpr int NSEG = NZP / LSEG;         // 85 (exact)
constexpr int TT   = COLS * NSEG;        // 197200 threads
constexpr float DT = 1e-3f;
constexpr float A2 = (float)((1.0 / 24.0) / 10.0);   // a/DX
constexpr float B2 = (float)((9.0 / 8.0) / 10.0);    // b/DX
constexpr float COEF = 0.43173470493638357f;         // -ln(1e-5)*3*4000/(2*(DX*NPAD)^2)

typedef float4 f4;
typedef float nf4 __attribute__((ext_vector_type(4)));   // native vector for nontemporal builtin

__device__ __forceinline__ f4 ld4(const float* p) { return *reinterpret_cast<const f4*>(p); }
__device__ __forceinline__ void st4(float* p, f4 v) { *reinterpret_cast<f4*>(p) = v; }
__device__ __forceinline__ void stnt4(float* p, f4 v) {
    nf4 w; w.x = v.x; w.y = v.y; w.z = v.z; w.w = v.w;
    __builtin_nontemporal_store(w, reinterpret_cast<nf4*>(p));
}
__device__ __forceinline__ void unp(float* w, f4 v) { w[0]=v.x; w[1]=v.y; w[2]=v.z; w[3]=v.w; }
__device__ __forceinline__ f4 mk4(const float* a) { return f4{a[0], a[1], a[2], a[3]}; }

__device__ __forceinline__ float dax_of(int j) {
    float ax = 1.0f;
    if (j < NPAD)                { int r = NPAD - 1 - j;      ax = COEF * (float)(r * r); }
    else if (j >= NX + NPAD)     { int r = j - (NX + NPAD);   ax = COEF * (float)(r * r); }
    return 1.0f - DT * ax;
}
__device__ __forceinline__ float daz_of(int i) {
    float az = 1.0f;
    if (i >= NZ)                 { int r = i - NZ;            az = COEF * (float)(r * r); }
    return 1.0f - DT * az;
}

// ---------------- Kernel 1: velocity update, z-march with register rings ----------------
__global__ __launch_bounds__(256) void k_vel(
    const float* __restrict__ txx, const float* __restrict__ tzz, const float* __restrict__ txz,
    const float* __restrict__ vx_x, const float* __restrict__ vx_z,
    const float* __restrict__ vz_x, const float* __restrict__ vz_z,
    const float* __restrict__ rho,
    const float* __restrict__ fs, const int* __restrict__ zs, const int* __restrict__ xs,
    float* __restrict__ out)
{
    int t = blockIdx.x * 256 + threadIdx.x;
    if (t >= TT) return;
    int col = t % COLS;           // consecutive in wave -> coalesced
    int seg = t / COLS;
    int q   = col % NQ;
    int bc  = col / NQ;
    int c   = bc % Cdim;
    int b   = bc / Cdim;
    int j0  = q * 4;
    int z0  = seg * LSEG;

    const float* TXX = txx + (long)bc * HW;
    const float* TZZ = tzz + (long)bc * HW;
    const float* TXZ = txz + (long)bc * HW;
    const float* RHO = rho + (long)b * HW;
    const bool hasL = (q > 0), hasR = (q < NQ - 1);
    const f4 z4 = {0.f, 0.f, 0.f, 0.f};

    int sz  = zs[c];
    int e_inj = xs[c] + NPAD - j0;        // inject into element e_inj if in [0,4)
    float fsb = fs[b];
    const bool inj = (e_inj >= 0 && e_inj < 4);

    auto ldC = [&](const float* F, int r) -> f4 {
        return (r >= 0 && r < NZP) ? ld4(F + r * NXP + j0) : z4;
    };

    // rings: ringX[k] = txz row (z0-2+k); ringZ[k] = tzz row (z0-1+k)  [center quads]
    float ringX[4][4], ringZ[4][4];
    #pragma unroll
    for (int k = 0; k < 4; ++k) {
        unp(ringX[k], ldC(TXZ, z0 - 2 + k));
        float tmp[4]; unp(tmp, ldC(TZZ, z0 - 1 + k));
        if (inj && (z0 - 1 + k) == sz) {
            #pragma unroll
            for (int m = 0; m < 4; ++m) if (m == e_inj) tmp[m] += fsb;
        }
        #pragma unroll
        for (int m = 0; m < 4; ++m) ringZ[k][m] = tmp[m];
    }

    float dax0[4];
    #pragma unroll
    for (int m = 0; m < 4; ++m) dax0[m] = dax_of(j0 + m);

    #pragma unroll
    for (int rr = 0; rr < LSEG; ++rr) {
        int r = z0 + rr;
        int p = r * NXP + j0;
        long gidx = (long)bc * HW + p;

        float wxx[12];
        unp(wxx,     hasL ? ld4(TXX + p - 4) : z4);
        unp(wxx + 4, ld4(TXX + p));
        unp(wxx + 8, hasR ? ld4(TXX + p + 4) : z4);

        float wxz[12];
        unp(wxz,     hasL ? ld4(TXZ + p - 4) : z4);
        #pragma unroll
        for (int m = 0; m < 4; ++m) wxz[4 + m] = ringX[(rr + 2) & 3][m];   // center row r
        unp(wxz + 8, hasR ? ld4(TXZ + p + 4) : z4);

        float rr4[4]; unp(rr4, ld4(RHO + p));
        float pxx[4], pxz[4], pzx[4], pzz[4];
        unp(pxx, ld4(vx_x + gidx));
        unp(pxz, ld4(vx_z + gidx));
        unp(pzx, ld4(vz_x + gidx));
        unp(pzz, ld4(vz_z + gidx));

        float daz = daz_of(r);
        float ovx[4], ovz[4], ovxx[4], ovxz[4], ovzx[4], ovzz[4];
        #pragma unroll
        for (int m = 0; m < 4; ++m) {
            float rinv = 1.0f / rr4[m];
            float var_txx_x = (A2 * (wxx[3 + m] - wxx[6 + m]) + B2 * (wxx[5 + m] - wxx[4 + m])) * rinv; // KX
            float var_txz_x = (A2 * (wxz[2 + m] - wxz[5 + m]) + B2 * (wxz[4 + m] - wxz[3 + m])) * rinv; // KXU
            float txz_im2 = ringX[(rr) & 3][m], txz_im1 = ringX[(rr + 1) & 3][m];
            float txz_0   = ringX[(rr + 2) & 3][m], txz_ip1 = ringX[(rr + 3) & 3][m];
            float tzz_im1 = ringZ[(rr) & 3][m], tzz_0   = ringZ[(rr + 1) & 3][m];
            float tzz_ip1 = ringZ[(rr + 2) & 3][m], tzz_ip2 = ringZ[(rr + 3) & 3][m];
            float var_txz_z = (A2 * (txz_im2 - txz_ip1) + B2 * (txz_0   - txz_im1)) * rinv; // KZU
            float var_tzz_z = (A2 * (tzz_im1 - tzz_ip2) + B2 * (tzz_ip1 - tzz_0  )) * rinv; // KZ

            float nvx_x = dax0[m] * pxx[m] + DT * var_txx_x;
            float nvx_z = daz     * pxz[m] + DT * var_txz_z;
            float nvz_x = dax0[m] * pzx[m] + DT * var_txz_x;
            float nvz_z = daz     * pzz[m] + DT * var_tzz_z;
            ovxx[m] = nvx_x; ovxz[m] = nvx_z; ovzx[m] = nvz_x; ovzz[m] = nvz_z;
            ovx[m] = nvx_x + nvx_z; ovz[m] = nvz_x + nvz_z;
        }

        st4  (out + 0 * (long)S + gidx, mk4(ovx));   // vx, vz stay cached (k_stress reads them)
        st4  (out + 1 * (long)S + gidx, mk4(ovz));
        stnt4(out + 5 * (long)S + gidx, mk4(ovxx));
        stnt4(out + 6 * (long)S + gidx, mk4(ovxz));
        stnt4(out + 7 * (long)S + gidx, mk4(ovzx));
        stnt4(out + 8 * (long)S + gidx, mk4(ovzz));

        if (rr < LSEG - 1) {   // advance rings (oldest slot = rr&3)
            unp(ringX[rr & 3], ldC(TXZ, r + 2));
            float tmp[4]; unp(tmp, ldC(TZZ, r + 3));
            if (inj && (r + 3) == sz) {
                #pragma unroll
                for (int m = 0; m < 4; ++m) if (m == e_inj) tmp[m] += fsb;
            }
            #pragma unroll
            for (int m = 0; m < 4; ++m) ringZ[rr & 3][m] = tmp[m];
        }
    }
}

// ---------------- Kernel 2: stress update, z-march with register rings ----------------
__global__ __launch_bounds__(256) void k_stress(
    const float* __restrict__ txx_x, const float* __restrict__ txx_z,
    const float* __restrict__ tzz_x, const float* __restrict__ tzz_z,
    const float* __restrict__ txz_x, const float* __restrict__ txz_z,
    const float* __restrict__ vp, const float* __restrict__ vs, const float* __restrict__ rho,
    float* __restrict__ out)
{
    int t = blockIdx.x * 256 + threadIdx.x;
    if (t >= TT) return;
    int col = t % COLS;
    int seg = t / COLS;
    int q   = col % NQ;
    int bc  = col / NQ;
    int b   = bc / Cdim;
    int j0  = q * 4;
    int z0  = seg * LSEG;

    const float* VX = out + 0 * (long)S + (long)bc * HW;
    const float* VZ = out + 1 * (long)S + (long)bc * HW;
    const bool hasL = (q > 0), hasR = (q < NQ - 1);
    const f4 z4 = {0.f, 0.f, 0.f, 0.f};

    auto ldC = [&](const float* F, int r) -> f4 {
        return (r >= 0 && r < NZP) ? ld4(F + r * NXP + j0) : z4;
    };

    // rings: ringVX[k] = vx row (z0-1+k) [KZ needs i-1..i+2]; ringVZ[k] = vz row (z0-2+k) [KZU needs i-2..i+1]
    float ringVX[4][4], ringVZ[4][4];
    #pragma unroll
    for (int k = 0; k < 4; ++k) {
        unp(ringVX[k], ldC(VX, z0 - 1 + k));
        unp(ringVZ[k], ldC(VZ, z0 - 2 + k));
    }

    float dax0[4];
    #pragma unroll
    for (int m = 0; m < 4; ++m) dax0[m] = dax_of(j0 + m);

    #pragma unroll
    for (int rr = 0; rr < LSEG; ++rr) {
        int r = z0 + rr;
        int p = r * NXP + j0;
        long gidx = (long)bc * HW + p;

        float wvx[12];
        unp(wvx,     hasL ? ld4(VX + p - 4) : z4);
        #pragma unroll
        for (int m = 0; m < 4; ++m) wvx[4 + m] = ringVX[(rr + 1) & 3][m];  // center row r
        unp(wvx + 8, hasR ? ld4(VX + p + 4) : z4);

        float wvz[12];
        unp(wvz,     hasL ? ld4(VZ + p - 4) : z4);
        #pragma unroll
        for (int m = 0; m < 4; ++m) wvz[4 + m] = ringVZ[(rr + 2) & 3][m];  // center row r
        unp(wvz + 8, hasR ? ld4(VZ + p + 4) : z4);

        long mp = (long)b * HW + p;
        float vpv[4], vsv[4], rh[4];
        unp(vpv, ld4(vp + mp));
        unp(vsv, ld4(vs + mp));
        unp(rh,  ld4(rho + mp));

        float pxxx[4], pxxz[4], pzzx[4], pzzz[4], pxzx[4], pxzz[4];
        unp(pxxx, ld4(txx_x + gidx));
        unp(pxxz, ld4(txx_z + gidx));
        unp(pzzx, ld4(tzz_x + gidx));
        unp(pzzz, ld4(tzz_z + gidx));
        unp(pxzx, ld4(txz_x + gidx));
        unp(pxzz, ld4(txz_z + gidx));

        float daz = daz_of(r);
        float o_txx[4], o_tzz[4], o_txz[4];
        float o_xxx[4], o_xxz[4], o_zzx[4], o_zzz[4], o_xzx[4], o_xzz[4];
        #pragma unroll
        for (int m = 0; m < 4; ++m) {
            float var_vx_x = A2 * (wvx[2 + m] - wvx[5 + m]) + B2 * (wvx[4 + m] - wvx[3 + m]); // KXU
            float var_vz_x = A2 * (wvz[3 + m] - wvz[6 + m]) + B2 * (wvz[5 + m] - wvz[4 + m]); // KX
            float vx_im1 = ringVX[(rr) & 3][m],     vx_0   = ringVX[(rr + 1) & 3][m];
            float vx_ip1 = ringVX[(rr + 2) & 3][m], vx_ip2 = ringVX[(rr + 3) & 3][m];
            float vz_im2 = ringVZ[(rr) & 3][m],     vz_im1 = ringVZ[(rr + 1) & 3][m];
            float vz_0   = ringVZ[(rr + 2) & 3][m], vz_ip1 = ringVZ[(rr + 3) & 3][m];
            float var_vx_z = A2 * (vx_im1 - vx_ip2) + B2 * (vx_ip1 - vx_0  ); // KZ
            float var_vz_z = A2 * (vz_im2 - vz_ip1) + B2 * (vz_0   - vz_im1); // KZU

            float lam2mu = vpv[m] * vpv[m] * rh[m];
            float mu     = vsv[m] * vsv[m] * rh[m];
            float lam    = lam2mu - 2.0f * mu;

            float ntxx_x = dax0[m] * pxxx[m] + DT * lam2mu * var_vx_x;
            float ntxx_z = daz     * pxxz[m] + DT * lam    * var_vz_z;
            float ntzz_x = dax0[m] * pzzx[m] + DT * lam    * var_vx_x;
            float ntzz_z = daz     * pzzz[m] + DT * lam2mu * var_vz_z;
            float ntxz_x = dax0[m] * pxzx[m] + DT * mu     * var_vz_x;
            float ntxz_z = daz     * pxzz[m] + DT * mu     * var_vx_z;

            o_txx[m] = ntxx_x + ntxx_z;
            o_tzz[m] = ntzz_x + ntzz_z;
            o_txz[m] = ntxz_x + ntxz_z;
            o_xxx[m] = ntxx_x; o_xxz[m] = ntxx_z;
            o_zzx[m] = ntzz_x; o_zzz[m] = ntzz_z;
            o_xzx[m] = ntxz_x; o_xzz[m] = ntxz_z;
        }

        stnt4(out +  2 * (long)S + gidx, mk4(o_txx));
        stnt4(out +  3 * (long)S + gidx, mk4(o_tzz));
        stnt4(out +  4 * (long)S + gidx, mk4(o_txz));
        stnt4(out +  9 * (long)S + gidx, mk4(o_xxx));
        stnt4(out + 10 * (long)S + gidx, mk4(o_xxz));
        stnt4(out + 11 * (long)S + gidx, mk4(o_zzx));
        stnt4(out + 12 * (long)S + gidx, mk4(o_zzz));
        stnt4(out + 13 * (long)S + gidx, mk4(o_xzx));
        stnt4(out + 14 * (long)S + gidx, mk4(o_xzz));

        if (rr < LSEG - 1) {   // advance rings
            unp(ringVX[rr & 3], ldC(VX, r + 3));
            unp(ringVZ[rr & 3], ldC(VZ, r + 2));
        }
    }
}

extern "C" void kernel_launch(void* const* d_in, const int* in_sizes, int n_in,
                              void* d_out, int out_size, void* d_ws, size_t ws_size,
                              hipStream_t stream) {
    const float* txx   = (const float*)d_in[0];
    const float* tzz   = (const float*)d_in[1];
    const float* txz   = (const float*)d_in[2];
    const float* vx_x  = (const float*)d_in[3];
    const float* vx_z  = (const float*)d_in[4];
    const float* vz_x  = (const float*)d_in[5];
    const float* vz_z  = (const float*)d_in[6];
    const float* txx_x = (const float*)d_in[7];
    const float* txx_z = (const float*)d_in[8];
    const float* tzz_x = (const float*)d_in[9];
    const float* tzz_z = (const float*)d_in[10];
    const float* txz_x = (const float*)d_in[11];
    const float* txz_z = (const float*)d_in[12];
    const float* vp    = (const float*)d_in[13];
    const float* vs    = (const float*)d_in[14];
    const float* rho   = (const float*)d_in[15];
    const float* fs    = (const float*)d_in[16];
    const int*   zs    = (const int*)d_in[17];
    const int*   xs    = (const int*)d_in[18];
    float* out = (float*)d_out;

    dim3 grid((TT + 255) / 256), block(256);
    k_vel<<<grid, block, 0, stream>>>(txx, tzz, txz, vx_x, vx_z, vz_x, vz_z,
                                      rho, fs, zs, xs, out);
    k_stress<<<grid, block, 0, stream>>>(txx_x, txx_z, tzz_x, tzz_z, txz_x, txz_z,
                                         vp, vs, rho, out);
}